// Round 18
// baseline (398.502 us; speedup 1.0000x reference)
//
#include <hip/hip_runtime.h>
#include <hip/hip_bf16.h>

// LRRNN: B=64, dz=16, K=16, N=1024, dx=128, T=500 (T derived on HOST from
// out_size = B*DX*T*KC -> grid sizing without device readback).
// R18: TWO-KERNEL SPLIT. Evidence: all fast single-kernel variants pin at
// 768-811 GB/s of stores = 12.3-12.6 GB/s per active CU (m13's per-CU write
// rate) -> the 64-block recurrence kernel is store-path throttled.
//  K1 (64 blocks, R17 skeleton minus readout): recurrence only; wave1 stores
//     the packed bf16 z (512B/step/block, 16.4MB total) to d_ws post-bar2.
//  K2 (B x 10 t-chunks = 640 blocks, 4 waves x 2 x-tiles): readout at
//     256-CU store BW. Per t: 8B zhist load (same fragment layout as zbuf)
//     -> 2 swapped MFMAs (z^T*Bobs, R17) -> 2 dwordx4 streaming stores.
// Kernel boundary = producer-consumer sync (no cross-block flag hazards).
// Fallback: if ws_size < 16.4MB, launch the R17 monolithic kernel.

typedef __attribute__((ext_vector_type(4))) short short4v;
typedef __attribute__((ext_vector_type(8))) short short8v;
typedef __attribute__((ext_vector_type(4))) float float4v;

#define BB 64
#define DZ 16
#define KC 16
#define NN 1024
#define DX 128
#define NW 8                    // waves per block (kernel 1)
#define ITER (NN / (16 * NW))   // 8 row-tiles per wave
#define NH (ITER / 2)           // 4 x32 n-MFMAs per wave
#define CS 50                   // t-chunk size (kernel 2)

// execution barrier + LDS publish; NO vmcnt drain
#define BARRIER_LGKM() asm volatile("s_waitcnt lgkmcnt(0)\n\ts_barrier" ::: "memory")

union FragAB {
  short4v s;
  __hip_bfloat162 h2[2];
};
union Frag8 {
  short8v s8;
  short4v s4[2];
};

__device__ inline short4v pack_bf16x4(float a, float b, float c, float d) {
  FragAB u;
  u.h2[0] = __float22bfloat162_rn(make_float2(a, b));
  u.h2[1] = __float22bfloat162_rn(make_float2(c, d));
  return u.s;
}

// every branch __has_builtin-guarded: the HOST pass must never see a branch
// whose builtin it can't resolve (falls through to never-executed asm).
__device__ inline float4v mfma_bf16(short4v a, short4v b, float4v c) {
#if __has_builtin(__builtin_amdgcn_mfma_f32_16x16x16bf16_1k)
  return __builtin_amdgcn_mfma_f32_16x16x16bf16_1k(a, b, c, 0, 0, 0);
#else
  float4v d;
  asm("v_mfma_f32_16x16x16_bf16 %0, %1, %2, %3"
      : "=v"(d) : "v"(a), "v"(b), "v"(c));
  return d;
#endif
}

__device__ inline float4v mfma_bf16_x32(short8v a, short8v b, float4v c) {
#if __has_builtin(__builtin_amdgcn_mfma_f32_16x16x32_bf16)
  return __builtin_amdgcn_mfma_f32_16x16x32_bf16(a, b, c, 0, 0, 0);
#else
  float4v d;
  asm("v_mfma_f32_16x16x32_bf16 %0, %1, %2, %3"
      : "=v"(d) : "v"(a), "v"(b), "v"(c));
  return d;
#endif
}

// ============================ KERNEL 1: recurrence ============================
__global__ __launch_bounds__(64 * NW, 2)
void lrrnn_recur(const float* __restrict__ z0, const float* __restrict__ Adec,
                 const float* __restrict__ nmat, const float* __restrict__ mmat,
                 const float* __restrict__ hvec, const float* __restrict__ hzvec,
                 int T, short4v* __restrict__ zhist)
{
  const int b    = blockIdx.x;
  const int tid  = threadIdx.x;
  const int wave = tid >> 6;
  const int lane = tid & 63;
  const int g    = lane >> 4;   // 0..3  (quad group)
  const int c    = lane & 15;   // 0..15 (column / row-in-tile)

  __shared__ float4v part[NW][64];   // single-buffered (R6/R10-proven safe)
  __shared__ short4v zbuf[64];       // packed bf16 z broadcast (8 B/lane)

  // ---- one-time fragment preload (weights shared across blocks; L2-resident) ----
  FragAB mf[ITER];
  Frag8  nf8[NH];
  float4v negH[ITER];
#pragma unroll
  for (int i = 0; i < ITER; ++i) {
    const int rowbase = wave * (16 * ITER) + i * 16;
    float4v mv = *(const float4v*)(mmat + (rowbase + c) * DZ + g * 4);
    mf[i].s = pack_bf16x4(mv[0], mv[1], mv[2], mv[3]);
    float4v hv = *(const float4v*)(hvec + rowbase + g * 4);
    negH[i][0] = -hv[0]; negH[i][1] = -hv[1];
    negH[i][2] = -hv[2]; negH[i][3] = -hv[3];
  }
#pragma unroll
  for (int i = 0; i < NH; ++i) {
    const int rb0 = wave * (16 * ITER) + (2 * i) * 16;
    float4v nv0 = *(const float4v*)(nmat + c * NN + rb0 + g * 4);
    float4v nv1 = *(const float4v*)(nmat + c * NN + rb0 + 16 + g * 4);
    nf8[i].s4[0] = pack_bf16x4(nv0[0], nv0[1], nv0[2], nv0[3]);
    nf8[i].s4[1] = pack_bf16x4(nv1[0], nv1[1], nv1[2], nv1[3]);
  }

  const float4v Af  = *(const float4v*)(Adec + g * 4);
  const float4v hzf = *(const float4v*)(hzvec + g * 4);
  const float4v zerov = {0.f, 0.f, 0.f, 0.f};

  // z state: f32 master in wave0 only; all waves track packed bf16 zb
  float4v zf;
#pragma unroll
  for (int j = 0; j < 4; ++j)
    zf[j] = z0[b * DZ * KC + (g * 4 + j) * KC + c];
  FragAB zb;
  zb.s = pack_bf16x4(zf[0], zf[1], zf[2], zf[3]);

  short4v* zh = zhist + (size_t)b * T * 64 + lane;

  for (int t = 0; t < T; ++t) {
    // ---- phase A: 8 indep X-MFMAs -> relu/pack -> 4x x32 n@R ----
    float4v xv[ITER];
#pragma unroll
    for (int i = 0; i < ITER; ++i)
      xv[i] = mfma_bf16(mf[i].s, zb.s, negH[i]);

    Frag8 R8[NH];
#pragma unroll
    for (int i = 0; i < NH; ++i) {
      const float4v x0 = xv[2 * i], x1 = xv[2 * i + 1];
      R8[i].s4[0] = pack_bf16x4(fmaxf(x0[0], 0.f), fmaxf(x0[1], 0.f),
                                fmaxf(x0[2], 0.f), fmaxf(x0[3], 0.f));
      R8[i].s4[1] = pack_bf16x4(fmaxf(x1[0], 0.f), fmaxf(x1[1], 0.f),
                                fmaxf(x1[2], 0.f), fmaxf(x1[3], 0.f));
    }

    float4v a0 = mfma_bf16_x32(nf8[0].s8, R8[0].s8, (wave == 0) ? hzf : zerov);
    float4v a1 = mfma_bf16_x32(nf8[1].s8, R8[1].s8, zerov);
    a0 = mfma_bf16_x32(nf8[2].s8, R8[2].s8, a0);
    a1 = mfma_bf16_x32(nf8[3].s8, R8[3].s8, a1);
    const float4v zp = a0 + a1;

    if (wave != 0) part[wave][lane] = zp;
    BARRIER_LGKM();    // barrier 1: partials published (no vmcnt drain)

    if (wave == 0) {
      const float4v p1 = part[1][lane];
      const float4v p2 = part[2][lane];
      const float4v p3 = part[3][lane];
      const float4v p4 = part[4][lane];
      const float4v p5 = part[5][lane];
      const float4v p6 = part[6][lane];
      const float4v p7 = part[7][lane];
      const float4v tot = ((zp + p1) + (p2 + p3)) + ((p4 + p5) + (p6 + p7));
#pragma unroll
      for (int j = 0; j < 4; ++j)
        zf[j] = fmaf(Af[j], zf[j], tot[j]);
      zb.s = pack_bf16x4(zf[0], zf[1], zf[2], zf[3]);
      zbuf[lane] = zb.s;
    }
    BARRIER_LGKM();    // barrier 2: zbuf published (no vmcnt drain)

    if (wave != 0) zb.s = zbuf[lane];   // 8 B broadcast (2-way alias: free)
    if (wave == 1) zh[t * 64] = zb.s;   // z-history store (off wave0's path)
  }
}

// ============================ KERNEL 2: readout ==============================
// out[b, x, t, k] = Bobs^T z_{t+1} + Bias, from zhist (packed bf16, zbuf
// fragment layout). Swapped MFMA (R17): A = zhist frag, B = bobsF, D[k][x]
// -> lane (g,c) holds 4 consecutive k of x=xb+c -> one dwordx4 per tile.
__global__ __launch_bounds__(256, 4)
void lrrnn_readout(const short4v* __restrict__ zhist,
                   const float* __restrict__ Bobs, const float* __restrict__ Bias,
                   int T, int tch, float* __restrict__ out)
{
  const int bx   = blockIdx.x;
  const int b    = bx / tch;
  const int ch   = bx - b * tch;
  const int tid  = threadIdx.x;
  const int wave = tid >> 6;      // 0..3, owns x-tiles {2w, 2w+1}
  const int lane = tid & 63;
  const int g    = lane >> 4;
  const int c    = lane & 15;

  FragAB bobsF[2];
  float4v biasF[2];
  unsigned oof[2];
#pragma unroll
  for (int s = 0; s < 2; ++s) {
    const int xb = (wave * 2 + s) * 16;
    bobsF[s].s = pack_bf16x4(Bobs[(4 * g + 0) * DX + xb + c],
                             Bobs[(4 * g + 1) * DX + xb + c],
                             Bobs[(4 * g + 2) * DX + xb + c],
                             Bobs[(4 * g + 3) * DX + xb + c]);
    const float bxv = Bias[xb + c];
    biasF[s][0] = bxv; biasF[s][1] = bxv; biasF[s][2] = bxv; biasF[s][3] = bxv;
    oof[s] = (unsigned)(b * DX + xb + c) * (unsigned)T * KC + (unsigned)(g * 4);
  }

  const short4v* zh = zhist + (size_t)b * T * 64 + lane;
  const int t0 = ch * CS;
  const int t1 = (t0 + CS < T) ? (t0 + CS) : T;

  for (int t = t0; t < t1; ++t) {
    const short4v za = zh[t * 64];
    const unsigned tk = (unsigned)t * KC;
#pragma unroll
    for (int s = 0; s < 2; ++s) {
      float4v o = mfma_bf16(za, bobsF[s].s, biasF[s]);
      *(float4v*)(out + oof[s] + tk) = o;
    }
  }
}

// ================== FALLBACK: R17 monolithic (ws too small) ==================
__global__ __launch_bounds__(64 * NW, 2)
void lrrnn_mono(const float* __restrict__ z0, const float* __restrict__ Adec,
                const float* __restrict__ nmat, const float* __restrict__ mmat,
                const float* __restrict__ hvec, const float* __restrict__ hzvec,
                const float* __restrict__ Bobs, const float* __restrict__ Bias,
                int T, float* __restrict__ out)
{
  const int b    = blockIdx.x;
  const int tid  = threadIdx.x;
  const int wave = tid >> 6;
  const int lane = tid & 63;
  const int g    = lane >> 4;
  const int c    = lane & 15;

  __shared__ float4v part[NW][64];
  __shared__ short4v zbuf[64];

  FragAB mf[ITER];
  Frag8  nf8[NH];
  float4v negH[ITER];
#pragma unroll
  for (int i = 0; i < ITER; ++i) {
    const int rowbase = wave * (16 * ITER) + i * 16;
    float4v mv = *(const float4v*)(mmat + (rowbase + c) * DZ + g * 4);
    mf[i].s = pack_bf16x4(mv[0], mv[1], mv[2], mv[3]);
    float4v hv = *(const float4v*)(hvec + rowbase + g * 4);
    negH[i][0] = -hv[0]; negH[i][1] = -hv[1];
    negH[i][2] = -hv[2]; negH[i][3] = -hv[3];
  }
#pragma unroll
  for (int i = 0; i < NH; ++i) {
    const int rb0 = wave * (16 * ITER) + (2 * i) * 16;
    float4v nv0 = *(const float4v*)(nmat + c * NN + rb0 + g * 4);
    float4v nv1 = *(const float4v*)(nmat + c * NN + rb0 + 16 + g * 4);
    nf8[i].s4[0] = pack_bf16x4(nv0[0], nv0[1], nv0[2], nv0[3]);
    nf8[i].s4[1] = pack_bf16x4(nv1[0], nv1[1], nv1[2], nv1[3]);
  }

  const float4v Af  = *(const float4v*)(Adec + g * 4);
  const float4v hzf = *(const float4v*)(hzvec + g * 4);
  const float4v zerov = {0.f, 0.f, 0.f, 0.f};

  const int t0i = (wave >= 1) ? (wave - 1) : 0;
  const int nt = (wave == 1) ? 2 : ((wave == 0) ? 0 : 1);
  int tiles[2] = {t0i, 7};
  FragAB bobsF[2];
  float4v biasF[2];
  unsigned oof[2];
#pragma unroll
  for (int s = 0; s < 2; ++s) {
    const int xb = tiles[s] * 16;
    bobsF[s].s = pack_bf16x4(Bobs[(4 * g + 0) * DX + xb + c],
                             Bobs[(4 * g + 1) * DX + xb + c],
                             Bobs[(4 * g + 2) * DX + xb + c],
                             Bobs[(4 * g + 3) * DX + xb + c]);
    const float bxv = Bias[xb + c];
    biasF[s][0] = bxv; biasF[s][1] = bxv; biasF[s][2] = bxv; biasF[s][3] = bxv;
    oof[s] = (unsigned)(b * DX + xb + c) * (unsigned)T * KC + (unsigned)(g * 4);
  }

  float4v zf;
#pragma unroll
  for (int j = 0; j < 4; ++j)
    zf[j] = z0[b * DZ * KC + (g * 4 + j) * KC + c];
  FragAB zb;
  zb.s = pack_bf16x4(zf[0], zf[1], zf[2], zf[3]);

  for (int t = 0; t < T; ++t) {
    float4v xv[ITER];
#pragma unroll
    for (int i = 0; i < ITER; ++i)
      xv[i] = mfma_bf16(mf[i].s, zb.s, negH[i]);

    Frag8 R8[NH];
#pragma unroll
    for (int i = 0; i < NH; ++i) {
      const float4v x0 = xv[2 * i], x1 = xv[2 * i + 1];
      R8[i].s4[0] = pack_bf16x4(fmaxf(x0[0], 0.f), fmaxf(x0[1], 0.f),
                                fmaxf(x0[2], 0.f), fmaxf(x0[3], 0.f));
      R8[i].s4[1] = pack_bf16x4(fmaxf(x1[0], 0.f), fmaxf(x1[1], 0.f),
                                fmaxf(x1[2], 0.f), fmaxf(x1[3], 0.f));
    }

    float4v a0 = mfma_bf16_x32(nf8[0].s8, R8[0].s8, (wave == 0) ? hzf : zerov);
    float4v a1 = mfma_bf16_x32(nf8[1].s8, R8[1].s8, zerov);
    a0 = mfma_bf16_x32(nf8[2].s8, R8[2].s8, a0);
    a1 = mfma_bf16_x32(nf8[3].s8, R8[3].s8, a1);
    const float4v zp = a0 + a1;

    if (wave != 0) part[wave][lane] = zp;
    BARRIER_LGKM();

    if (wave == 0) {
      const float4v p1 = part[1][lane];
      const float4v p2 = part[2][lane];
      const float4v p3 = part[3][lane];
      const float4v p4 = part[4][lane];
      const float4v p5 = part[5][lane];
      const float4v p6 = part[6][lane];
      const float4v p7 = part[7][lane];
      const float4v tot = ((zp + p1) + (p2 + p3)) + ((p4 + p5) + (p6 + p7));
#pragma unroll
      for (int j = 0; j < 4; ++j)
        zf[j] = fmaf(Af[j], zf[j], tot[j]);
      zb.s = pack_bf16x4(zf[0], zf[1], zf[2], zf[3]);
      zbuf[lane] = zb.s;
    } else if (t > 0) {
      const unsigned tk = (unsigned)(t - 1) * KC;
#pragma unroll
      for (int s = 0; s < 2; ++s) {
        if (s < nt) {
          float4v o = mfma_bf16(zb.s, bobsF[s].s, biasF[s]);
          *(float4v*)(out + oof[s] + tk) = o;
        }
      }
    }
    BARRIER_LGKM();

    if (wave != 0) zb.s = zbuf[lane];
  }

  if (wave != 0) {
    const unsigned tk = (unsigned)(T - 1) * KC;
#pragma unroll
    for (int s = 0; s < 2; ++s) {
      if (s < nt) {
        float4v o = mfma_bf16(zb.s, bobsF[s].s, biasF[s]);
        *(float4v*)(out + oof[s] + tk) = o;
      }
    }
  }
}

extern "C" void kernel_launch(void* const* d_in, const int* in_sizes, int n_in,
                              void* d_out, int out_size, void* d_ws, size_t ws_size,
                              hipStream_t stream) {
  const float* z0   = (const float*)d_in[0];
  const float* A    = (const float*)d_in[1];
  const float* nmat = (const float*)d_in[2];
  const float* mmat = (const float*)d_in[3];
  const float* h    = (const float*)d_in[4];
  const float* hz   = (const float*)d_in[5];
  const float* Bobs = (const float*)d_in[6];
  const float* Bias = (const float*)d_in[7];
  (void)in_sizes; (void)n_in;

  // T from out_size (host-side, deterministic): out = [B, DX, T, KC]
  const int T = out_size / (BB * DX * KC);
  const size_t need = (size_t)BB * T * 64 * sizeof(short4v);   // 16.4 MB @ T=500

  if (ws_size >= need) {
    short4v* zhist = (short4v*)d_ws;
    lrrnn_recur<<<dim3(BB), dim3(64 * NW), 0, stream>>>(
        z0, A, nmat, mmat, h, hz, T, zhist);
    const int tch = (T + CS - 1) / CS;
    lrrnn_readout<<<dim3(BB * tch), dim3(256), 0, stream>>>(
        zhist, Bobs, Bias, T, tch, (float*)d_out);
  } else {
    lrrnn_mono<<<dim3(BB), dim3(64 * NW), 0, stream>>>(
        z0, A, nmat, mmat, h, hz, Bobs, Bias, T, (float*)d_out);
  }
}

// Round 19
// 356.626 us; speedup vs baseline: 1.1174x; 1.1174x over previous
//
#include <hip/hip_runtime.h>
#include <hip/hip_bf16.h>

// LRRNN: B=64, dz=16, K=16, N=1024, dx=128, T=500 (T read from input 8).
// R19: 16 WAVES (1024 thr, 4 waves/SIMD) x 64 N-rows. R18's split proved the
// floor is the recurrence itself (~1600cyc/step even with 16MB stores); the
// unexplained ~800cyc is rendezvous/restart cost at 2 waves/SIMD (a wave
// stalled at s_barrier leaves its SIMD idle). 4 waves/SIMD soaks that.
// Skeleton (R13/R17, champion): phase A (4 indep X-MFMAs -> relu/pack ->
// 2x x32 n@R) -> lgkm-bar -> wave0 window (15-partial reduce + z update +
// packed zbuf broadcast) overlapped with waves 1-8 lagged readout (swapped
// z^T*Bobs MFMA -> ONE dwordx4 store/tile, R17) -> lgkm-bar -> 8B zbuf read.

typedef __attribute__((ext_vector_type(4))) short short4v;
typedef __attribute__((ext_vector_type(8))) short short8v;
typedef __attribute__((ext_vector_type(4))) float float4v;

#define BB 64
#define DZ 16
#define KC 16
#define NN 1024
#define DX 128
#define NW 16                   // waves per block
#define ITER (NN / (16 * NW))   // 4 row-tiles per wave
#define NH (ITER / 2)           // 2 x32 n-MFMAs per wave

// execution barrier + LDS publish; NO vmcnt drain
#define BARRIER_LGKM() asm volatile("s_waitcnt lgkmcnt(0)\n\ts_barrier" ::: "memory")

union FragAB {
  short4v s;
  __hip_bfloat162 h2[2];
};
union Frag8 {
  short8v s8;
  short4v s4[2];
};

__device__ inline short4v pack_bf16x4(float a, float b, float c, float d) {
  FragAB u;
  u.h2[0] = __float22bfloat162_rn(make_float2(a, b));
  u.h2[1] = __float22bfloat162_rn(make_float2(c, d));
  return u.s;
}

// every branch __has_builtin-guarded: the HOST pass must never see a branch
// whose builtin it can't resolve (falls through to never-executed asm).
__device__ inline float4v mfma_bf16(short4v a, short4v b, float4v c) {
#if __has_builtin(__builtin_amdgcn_mfma_f32_16x16x16bf16_1k)
  return __builtin_amdgcn_mfma_f32_16x16x16bf16_1k(a, b, c, 0, 0, 0);
#else
  float4v d;
  asm("v_mfma_f32_16x16x16_bf16 %0, %1, %2, %3"
      : "=v"(d) : "v"(a), "v"(b), "v"(c));
  return d;
#endif
}

__device__ inline float4v mfma_bf16_x32(short8v a, short8v b, float4v c) {
#if __has_builtin(__builtin_amdgcn_mfma_f32_16x16x32_bf16)
  return __builtin_amdgcn_mfma_f32_16x16x32_bf16(a, b, c, 0, 0, 0);
#else
  float4v d;
  asm("v_mfma_f32_16x16x32_bf16 %0, %1, %2, %3"
      : "=v"(d) : "v"(a), "v"(b), "v"(c));
  return d;
#endif
}

__global__ __launch_bounds__(64 * NW, 1)
void lrrnn_fused(const float* __restrict__ z0, const float* __restrict__ Adec,
                 const float* __restrict__ nmat, const float* __restrict__ mmat,
                 const float* __restrict__ hvec, const float* __restrict__ hzvec,
                 const float* __restrict__ Bobs, const float* __restrict__ Bias,
                 const int* __restrict__ Tptr, float* __restrict__ out)
{
  const int T    = Tptr[0];
  const int b    = blockIdx.x;
  const int tid  = threadIdx.x;
  const int wave = tid >> 6;
  const int lane = tid & 63;
  const int g    = lane >> 4;   // 0..3  (quad group)
  const int c    = lane & 15;   // 0..15 (column / row-in-tile)

  // single-buffered partials: wave0's reads complete before its lgkm+bar2;
  // peers' next writes are post-bar2 (R6/R10-proven).
  __shared__ float4v part[NW][64];   // 16 KB
  __shared__ short4v zbuf[64];       // packed bf16 z broadcast (8 B/lane)

  // ---- one-time fragment preload (weights shared across blocks; L2-resident) ----
  // m A-frag (x16): A[row=c][k=4g+j] = m[(rowbase+c)*16 + 4g+j]
  // n A-frag (x32): slot j<4 -> n[c*1024 + rb+4g+j], j>=4 -> n[c*1024 + rb+16+4g+j-4]
  // negH C-frag: C[row=4g+r][col] = -h[rowbase + 4g+r]
  FragAB mf[ITER];
  Frag8  nf8[NH];
  float4v negH[ITER];
#pragma unroll
  for (int i = 0; i < ITER; ++i) {
    const int rowbase = wave * (16 * ITER) + i * 16;
    float4v mv = *(const float4v*)(mmat + (rowbase + c) * DZ + g * 4);
    mf[i].s = pack_bf16x4(mv[0], mv[1], mv[2], mv[3]);
    float4v hv = *(const float4v*)(hvec + rowbase + g * 4);
    negH[i][0] = -hv[0]; negH[i][1] = -hv[1];
    negH[i][2] = -hv[2]; negH[i][3] = -hv[3];
  }
#pragma unroll
  for (int i = 0; i < NH; ++i) {
    const int rb0 = wave * (16 * ITER) + (2 * i) * 16;
    float4v nv0 = *(const float4v*)(nmat + c * NN + rb0 + g * 4);
    float4v nv1 = *(const float4v*)(nmat + c * NN + rb0 + 16 + g * 4);
    nf8[i].s4[0] = pack_bf16x4(nv0[0], nv0[1], nv0[2], nv0[3]);
    nf8[i].s4[1] = pack_bf16x4(nv1[0], nv1[1], nv1[2], nv1[3]);
  }

  // decay / bias-z frags (C-layout rows = z = 4g+r); wave0 is the z owner
  const float4v Af  = *(const float4v*)(Adec + g * 4);
  const float4v hzf = *(const float4v*)(hzvec + g * 4);
  const float4v zerov = {0.f, 0.f, 0.f, 0.f};

  // ---- readout: waves 1..8 own x-tile (wave-1); others none.
  // SWAPPED form (R17): A = zb, B[kk=4g+j][x=c] = Bobs[(4g+j)*128 + xb+c],
  // C = Bias[xb+c] replicated; D[k=4g+rr][x=c] -> one dwordx4 per tile.
  const int nt = (wave >= 1 && wave <= 8) ? 1 : 0;
  FragAB bobsF;
  float4v biasF;
  unsigned oof = 0;
  if (nt) {
    const int xb = (wave - 1) * 16;
    bobsF.s = pack_bf16x4(Bobs[(4 * g + 0) * DX + xb + c],
                          Bobs[(4 * g + 1) * DX + xb + c],
                          Bobs[(4 * g + 2) * DX + xb + c],
                          Bobs[(4 * g + 3) * DX + xb + c]);
    const float bxv = Bias[xb + c];
    biasF[0] = bxv; biasF[1] = bxv; biasF[2] = bxv; biasF[3] = bxv;
    oof = (unsigned)(b * DX + xb + c) * (unsigned)T * KC + (unsigned)(g * 4);
  } else {
    bobsF.s = (short4v){0, 0, 0, 0};
    biasF = zerov;
  }

  // z state: f32 master in wave0 only; all waves track packed bf16 zb
  float4v zf;
#pragma unroll
  for (int j = 0; j < 4; ++j)
    zf[j] = z0[b * DZ * KC + (g * 4 + j) * KC + c];
  FragAB zb;
  zb.s = pack_bf16x4(zf[0], zf[1], zf[2], zf[3]);

  for (int t = 0; t < T; ++t) {
    // ---- phase A: 4 indep X-MFMAs -> relu/pack -> 2x x32 n@R ----
    float4v xv[ITER];
#pragma unroll
    for (int i = 0; i < ITER; ++i)
      xv[i] = mfma_bf16(mf[i].s, zb.s, negH[i]);

    Frag8 R8[NH];
#pragma unroll
    for (int i = 0; i < NH; ++i) {
      const float4v x0 = xv[2 * i], x1 = xv[2 * i + 1];
      R8[i].s4[0] = pack_bf16x4(fmaxf(x0[0], 0.f), fmaxf(x0[1], 0.f),
                                fmaxf(x0[2], 0.f), fmaxf(x0[3], 0.f));
      R8[i].s4[1] = pack_bf16x4(fmaxf(x1[0], 0.f), fmaxf(x1[1], 0.f),
                                fmaxf(x1[2], 0.f), fmaxf(x1[3], 0.f));
    }

    float4v a0 = mfma_bf16_x32(nf8[0].s8, R8[0].s8, (wave == 0) ? hzf : zerov);
    float4v a1 = mfma_bf16_x32(nf8[1].s8, R8[1].s8, zerov);
    const float4v zp = a0 + a1;

    if (wave != 0) part[wave][lane] = zp;
    BARRIER_LGKM();    // barrier 1: partials published (no vmcnt drain)

    if (wave == 0) {
      // ---- reduce 15 partials + z update + broadcast (the serial window) ----
      const float4v p1  = part[1][lane],  p2  = part[2][lane];
      const float4v p3  = part[3][lane],  p4  = part[4][lane];
      const float4v p5  = part[5][lane],  p6  = part[6][lane];
      const float4v p7  = part[7][lane],  p8  = part[8][lane];
      const float4v p9  = part[9][lane],  p10 = part[10][lane];
      const float4v p11 = part[11][lane], p12 = part[12][lane];
      const float4v p13 = part[13][lane], p14 = part[14][lane];
      const float4v p15 = part[15][lane];
      const float4v s0 = ((zp + p1) + (p2 + p3)) + ((p4 + p5) + (p6 + p7));
      const float4v s1 = ((p8 + p9) + (p10 + p11)) + ((p12 + p13) + (p14 + p15));
      const float4v tot = s0 + s1;
#pragma unroll
      for (int j = 0; j < 4; ++j)
        zf[j] = fmaf(Af[j], zf[j], tot[j]);
      zb.s = pack_bf16x4(zf[0], zf[1], zf[2], zf[3]);
      zbuf[lane] = zb.s;
    } else if (nt && t > 0) {
      // ---- lagged readout fills the window: zb = z_t -> out index t-1 ----
      float4v o = mfma_bf16(zb.s, bobsF.s, biasF);   // SWAPPED
      *(float4v*)(out + oof + (unsigned)(t - 1) * KC) = o;
    }
    BARRIER_LGKM();    // barrier 2: zbuf published (no vmcnt drain)

    if (wave != 0) zb.s = zbuf[lane];   // 8 B broadcast (2-way alias: free)
  }

  // ---- epilogue: final readout, index T-1 from zb = z_T ----
  if (nt) {
    float4v o = mfma_bf16(zb.s, bobsF.s, biasF);     // SWAPPED
    *(float4v*)(out + oof + (unsigned)(T - 1) * KC) = o;
  }
}

extern "C" void kernel_launch(void* const* d_in, const int* in_sizes, int n_in,
                              void* d_out, int out_size, void* d_ws, size_t ws_size,
                              hipStream_t stream) {
  const float* z0   = (const float*)d_in[0];
  const float* A    = (const float*)d_in[1];
  const float* nmat = (const float*)d_in[2];
  const float* mmat = (const float*)d_in[3];
  const float* h    = (const float*)d_in[4];
  const float* hz   = (const float*)d_in[5];
  const float* Bobs = (const float*)d_in[6];
  const float* Bias = (const float*)d_in[7];
  const int*   T    = (const int*)d_in[8];
  (void)in_sizes; (void)n_in; (void)out_size; (void)d_ws; (void)ws_size;
  lrrnn_fused<<<dim3(BB), dim3(64 * NW), 0, stream>>>(
      z0, A, nmat, mmat, h, hz, Bobs, Bias, T, (float*)d_out);
}

// Round 20
// 321.310 us; speedup vs baseline: 1.2402x; 1.1099x over previous
//
#include <hip/hip_runtime.h>
#include <hip/hip_bf16.h>

// LRRNN: B=64, dz=16, K=16, N=1024, dx=128, T=500 (T read from input 8).
// 64 blocks, 8 waves x 128 N-rows, 2 waves/SIMD (occupancy set by the
// 64-block grid: at most ONE block per CU, ever). R17 skeleton (champion,
// 323us): phase A (8 indep X-MFMAs -> relu/pack -> 4x x32 n@R) -> lgkm-bar
// -> wave0 window (reduce + z update + packed zbuf broadcast) overlapped
// with waves 1-7 lagged readout (swapped z^T*Bobs MFMA -> ONE dwordx4 store
// per tile) -> lgkm-bar -> 8B zbuf read. lgkm-only barriers.
// R20 = R17 with __launch_bounds__(512, 1): the old ",2" promised 2 waves/
// SIMD min -> ~256-reg/wave cap -> compiler banked weights in AGPRs, paying
// v_accvgpr round trips for every VALU-touching value (suspected phantom
// VALU: measured ~770 cyc/SIMD/step vs ~320 static). A second block never
// co-resides (64 blocks, 256 CUs), so the relaxed bound changes nothing
// about real occupancy -- only the register budget.

typedef __attribute__((ext_vector_type(4))) short short4v;
typedef __attribute__((ext_vector_type(8))) short short8v;
typedef __attribute__((ext_vector_type(4))) float float4v;

#define BB 64
#define DZ 16
#define KC 16
#define NN 1024
#define DX 128
#define NW 8                    // waves per block
#define ITER (NN / (16 * NW))   // 8 row-tiles per wave
#define NH (ITER / 2)           // 4 x32 n-MFMAs per wave

// execution barrier + LDS publish; NO vmcnt drain
#define BARRIER_LGKM() asm volatile("s_waitcnt lgkmcnt(0)\n\ts_barrier" ::: "memory")

union FragAB {
  short4v s;
  __hip_bfloat162 h2[2];
};
union Frag8 {
  short8v s8;
  short4v s4[2];
};

__device__ inline short4v pack_bf16x4(float a, float b, float c, float d) {
  FragAB u;
  u.h2[0] = __float22bfloat162_rn(make_float2(a, b));
  u.h2[1] = __float22bfloat162_rn(make_float2(c, d));
  return u.s;
}

// every branch __has_builtin-guarded: the HOST pass must never see a branch
// whose builtin it can't resolve (falls through to never-executed asm).
__device__ inline float4v mfma_bf16(short4v a, short4v b, float4v c) {
#if __has_builtin(__builtin_amdgcn_mfma_f32_16x16x16bf16_1k)
  return __builtin_amdgcn_mfma_f32_16x16x16bf16_1k(a, b, c, 0, 0, 0);
#else
  float4v d;
  asm("v_mfma_f32_16x16x16_bf16 %0, %1, %2, %3"
      : "=v"(d) : "v"(a), "v"(b), "v"(c));
  return d;
#endif
}

__device__ inline float4v mfma_bf16_x32(short8v a, short8v b, float4v c) {
#if __has_builtin(__builtin_amdgcn_mfma_f32_16x16x32_bf16)
  return __builtin_amdgcn_mfma_f32_16x16x32_bf16(a, b, c, 0, 0, 0);
#else
  float4v d;
  asm("v_mfma_f32_16x16x32_bf16 %0, %1, %2, %3"
      : "=v"(d) : "v"(a), "v"(b), "v"(c));
  return d;
#endif
}

__global__ __launch_bounds__(64 * NW, 1)
void lrrnn_fused(const float* __restrict__ z0, const float* __restrict__ Adec,
                 const float* __restrict__ nmat, const float* __restrict__ mmat,
                 const float* __restrict__ hvec, const float* __restrict__ hzvec,
                 const float* __restrict__ Bobs, const float* __restrict__ Bias,
                 const int* __restrict__ Tptr, float* __restrict__ out)
{
  const int T    = Tptr[0];
  const int b    = blockIdx.x;
  const int tid  = threadIdx.x;
  const int wave = tid >> 6;
  const int lane = tid & 63;
  const int g    = lane >> 4;   // 0..3  (quad group)
  const int c    = lane & 15;   // 0..15 (column / row-in-tile)

  // single-buffered partials: wave0's reads complete before its lgkm+bar2;
  // peers' next writes are post-bar2 (R6/R10-proven).
  __shared__ float4v part[NW][64];
  __shared__ short4v zbuf[64];       // packed bf16 z broadcast (8 B/lane)

  // ---- one-time fragment preload (weights shared across blocks; L2-resident) ----
  // m A-frag (x16): A[row=c][k=4g+j] = m[(rowbase+c)*16 + 4g+j]
  // n A-frag (x32): slot j<4 -> n[c*1024 + rb+4g+j], j>=4 -> n[c*1024 + rb+16+4g+j-4]
  // negH C-frag: C[row=4g+r][col] = -h[rowbase + 4g+r]
  FragAB mf[ITER];
  Frag8  nf8[NH];
  float4v negH[ITER];
#pragma unroll
  for (int i = 0; i < ITER; ++i) {
    const int rowbase = wave * (16 * ITER) + i * 16;
    float4v mv = *(const float4v*)(mmat + (rowbase + c) * DZ + g * 4);
    mf[i].s = pack_bf16x4(mv[0], mv[1], mv[2], mv[3]);
    float4v hv = *(const float4v*)(hvec + rowbase + g * 4);
    negH[i][0] = -hv[0]; negH[i][1] = -hv[1];
    negH[i][2] = -hv[2]; negH[i][3] = -hv[3];
  }
#pragma unroll
  for (int i = 0; i < NH; ++i) {
    const int rb0 = wave * (16 * ITER) + (2 * i) * 16;
    float4v nv0 = *(const float4v*)(nmat + c * NN + rb0 + g * 4);
    float4v nv1 = *(const float4v*)(nmat + c * NN + rb0 + 16 + g * 4);
    nf8[i].s4[0] = pack_bf16x4(nv0[0], nv0[1], nv0[2], nv0[3]);
    nf8[i].s4[1] = pack_bf16x4(nv1[0], nv1[1], nv1[2], nv1[3]);
  }

  // decay / bias-z frags (C-layout rows = z = 4g+r); wave0 is the z owner
  const float4v Af  = *(const float4v*)(Adec + g * 4);
  const float4v hzf = *(const float4v*)(hzvec + g * 4);
  const float4v zerov = {0.f, 0.f, 0.f, 0.f};

  // ---- readout tiles: tile tau handled by wave (tau%7)+1; wave1 also has
  // tile 7. wave0 does none (it owns the reduce window).
  // SWAPPED readout (R17): A = zb, B[kk=4g+j][x=c] = Bobs[(4g+j)*128+xb+c],
  // C = Bias[xb+c] replicated; D[k=4g+rr][x=c] -> one dwordx4 per tile.
  const int t0 = (wave >= 1) ? (wave - 1) : 0;
  const int nt = (wave == 1) ? 2 : ((wave == 0) ? 0 : 1);
  int tiles[2] = {t0, 7};
  FragAB bobsF[2];
  float4v biasF[2];
  unsigned oof[2];               // element offset of (x=xb+c, t=0, k=4g)
#pragma unroll
  for (int s = 0; s < 2; ++s) {
    const int xb = tiles[s] * 16;
    bobsF[s].s = pack_bf16x4(Bobs[(4 * g + 0) * DX + xb + c],
                             Bobs[(4 * g + 1) * DX + xb + c],
                             Bobs[(4 * g + 2) * DX + xb + c],
                             Bobs[(4 * g + 3) * DX + xb + c]);
    const float bx = Bias[xb + c];
    biasF[s][0] = bx; biasF[s][1] = bx; biasF[s][2] = bx; biasF[s][3] = bx;
    oof[s] = (unsigned)(b * DX + xb + c) * (unsigned)T * KC + (unsigned)(g * 4);
  }

  // z state: f32 master in wave0 only; all waves track packed bf16 zb
  float4v zf;
#pragma unroll
  for (int j = 0; j < 4; ++j)
    zf[j] = z0[b * DZ * KC + (g * 4 + j) * KC + c];
  FragAB zb;
  zb.s = pack_bf16x4(zf[0], zf[1], zf[2], zf[3]);

  for (int t = 0; t < T; ++t) {
    // ---- phase A: 8 indep X-MFMAs -> relu/pack -> 4x x32 n@R ----
    float4v xv[ITER];
#pragma unroll
    for (int i = 0; i < ITER; ++i)
      xv[i] = mfma_bf16(mf[i].s, zb.s, negH[i]);

    Frag8 R8[NH];
#pragma unroll
    for (int i = 0; i < NH; ++i) {
      const float4v x0 = xv[2 * i], x1 = xv[2 * i + 1];
      R8[i].s4[0] = pack_bf16x4(fmaxf(x0[0], 0.f), fmaxf(x0[1], 0.f),
                                fmaxf(x0[2], 0.f), fmaxf(x0[3], 0.f));
      R8[i].s4[1] = pack_bf16x4(fmaxf(x1[0], 0.f), fmaxf(x1[1], 0.f),
                                fmaxf(x1[2], 0.f), fmaxf(x1[3], 0.f));
    }

    float4v a0 = mfma_bf16_x32(nf8[0].s8, R8[0].s8, (wave == 0) ? hzf : zerov);
    float4v a1 = mfma_bf16_x32(nf8[1].s8, R8[1].s8, zerov);
    a0 = mfma_bf16_x32(nf8[2].s8, R8[2].s8, a0);
    a1 = mfma_bf16_x32(nf8[3].s8, R8[3].s8, a1);
    const float4v zp = a0 + a1;

    if (wave != 0) part[wave][lane] = zp;
    BARRIER_LGKM();    // barrier 1: partials published (no vmcnt drain)

    if (wave == 0) {
      // ---- reduce + z update + broadcast (the serial window) ----
      const float4v p1 = part[1][lane];
      const float4v p2 = part[2][lane];
      const float4v p3 = part[3][lane];
      const float4v p4 = part[4][lane];
      const float4v p5 = part[5][lane];
      const float4v p6 = part[6][lane];
      const float4v p7 = part[7][lane];
      const float4v tot = ((zp + p1) + (p2 + p3)) + ((p4 + p5) + (p6 + p7));
#pragma unroll
      for (int j = 0; j < 4; ++j)
        zf[j] = fmaf(Af[j], zf[j], tot[j]);
      zb.s = pack_bf16x4(zf[0], zf[1], zf[2], zf[3]);
      zbuf[lane] = zb.s;
    } else if (t > 0) {
      // ---- lagged readout fills the window: zb = z_t -> out index t-1 ----
      const unsigned tk = (unsigned)(t - 1) * KC;
#pragma unroll
      for (int s = 0; s < 2; ++s) {
        if (s < nt) {
          float4v o = mfma_bf16(zb.s, bobsF[s].s, biasF[s]);  // SWAPPED
          *(float4v*)(out + oof[s] + tk) = o;                 // 16B store
        }
      }
    }
    BARRIER_LGKM();    // barrier 2: zbuf published (no vmcnt drain)

    if (wave != 0) zb.s = zbuf[lane];   // 8 B broadcast (2-way alias: free)
  }

  // ---- epilogue: final readout, index T-1 from zb = z_T ----
  if (wave != 0) {
    const unsigned tk = (unsigned)(T - 1) * KC;
#pragma unroll
    for (int s = 0; s < 2; ++s) {
      if (s < nt) {
        float4v o = mfma_bf16(zb.s, bobsF[s].s, biasF[s]);    // SWAPPED
        *(float4v*)(out + oof[s] + tk) = o;                   // 16B store
      }
    }
  }
}

extern "C" void kernel_launch(void* const* d_in, const int* in_sizes, int n_in,
                              void* d_out, int out_size, void* d_ws, size_t ws_size,
                              hipStream_t stream) {
  const float* z0   = (const float*)d_in[0];
  const float* A    = (const float*)d_in[1];
  const float* nmat = (const float*)d_in[2];
  const float* mmat = (const float*)d_in[3];
  const float* h    = (const float*)d_in[4];
  const float* hz   = (const float*)d_in[5];
  const float* Bobs = (const float*)d_in[6];
  const float* Bias = (const float*)d_in[7];
  const int*   T    = (const int*)d_in[8];
  (void)in_sizes; (void)n_in; (void)out_size; (void)d_ws; (void)ws_size;
  lrrnn_fused<<<dim3(BB), dim3(64 * NW), 0, stream>>>(
      z0, A, nmat, mmat, h, hz, Bobs, Bias, T, (float*)d_out);
}